// Round 11
// baseline (632.077 us; speedup 1.0000x reference)
//
#include <hip/hip_runtime.h>
#include <hip/hip_bf16.h>

#define ALPHA   0.1f
#define S_DECAY 0.95f
#define P_DECAY 0.99f
#define D_EMB   768
#define DK      256

// ---- DPP wave-64 reduction helpers (validated rounds 1-8) ----
template<int ctrl, int row_mask>
__device__ __forceinline__ float dpp_add(float x) {
    int y = __builtin_amdgcn_update_dpp(0, __float_as_int(x), ctrl, row_mask, 0xF, true);
    return x + __int_as_float(y);
}

template<int N>
__device__ __forceinline__ void wave_allred_arr(float (&x)[N]) {
#pragma unroll
    for (int n = 0; n < N; ++n) x[n] = dpp_add<0xB1,  0xF>(x[n]);
#pragma unroll
    for (int n = 0; n < N; ++n) x[n] = dpp_add<0x4E,  0xF>(x[n]);
#pragma unroll
    for (int n = 0; n < N; ++n) x[n] = dpp_add<0x141, 0xF>(x[n]);
#pragma unroll
    for (int n = 0; n < N; ++n) x[n] = dpp_add<0x140, 0xF>(x[n]);
#pragma unroll
    for (int n = 0; n < N; ++n) x[n] = dpp_add<0x142, 0xA>(x[n]);
#pragma unroll
    for (int n = 0; n < N; ++n) x[n] = dpp_add<0x143, 0xC>(x[n]);
#pragma unroll
    for (int n = 0; n < N; ++n)
        x[n] = __int_as_float(__builtin_amdgcn_readlane(__float_as_int(x[n]), 63));
}

__device__ __forceinline__ float dot4v(const float4& a, const float4& b) {
    float t0 = a.x * b.x; t0 = fmaf(a.y, b.y, t0);
    float t1 = a.z * b.z; t1 = fmaf(a.w, b.w, t1);
    return t0 + t1;
}

__device__ __forceinline__ float rl(float x, int lane) {
    return __int_as_float(__builtin_amdgcn_readlane(__float_as_int(x), lane));
}

// ---------------- Kernel 1: GEMM, 4 rows x ONE matrix per block (validated, UNCHANGED) ----------------
__global__ __launch_bounds__(256) void prep_kernel(
    const float* __restrict__ emb,
    const float* __restrict__ Wk, const float* __restrict__ bk,
    const float* __restrict__ Wv, const float* __restrict__ bv,
    float* __restrict__ K, float* __restrict__ V, float* __restrict__ USrev,
    float* __restrict__ out, int T)
{
    const int tid = threadIdx.x;
    const int bid = blockIdx.x;
    const int NBLK = (T / 4) * 2;
    if (bid >= NBLK) {
        const int PADS = ((T + 63) / 64) * 64;
        for (int i = tid; i < (PADS - T) * DK; i += 256) USrev[(size_t)T * DK + i] = 0.f;
        out[tid] = 0.f;
        return;
    }
    const int mat = bid & 1;
    const int r0  = (bid >> 1) * 4;

    __shared__ float se[4][D_EMB];
    __shared__ float s_red[4][4];

    const float4* emb4 = reinterpret_cast<const float4*>(emb);
#pragma unroll
    for (int r = 0; r < 4; ++r) {
        if (tid < D_EMB / 4)
            reinterpret_cast<float4*>(se[r])[tid] = emb4[(size_t)(r0 + r) * (D_EMB / 4) + tid];
    }
    __syncthreads();

    const float* Wp = mat ? Wv : Wk;
    const float* bp = mat ? bv : bk;
    const int j = tid;

    float a0 = 0.f, a1 = 0.f, a2 = 0.f, a3 = 0.f;
    float c0 = Wp[j],        c1 = Wp[j + DK],     c2 = Wp[j + 2*DK], c3 = Wp[j + 3*DK];
    float p0 = Wp[j + 4*DK], p1 = Wp[j + 5*DK],   p2 = Wp[j + 6*DK], p3 = Wp[j + 7*DK];

    for (int d = 0; d < D_EMB; d += 4) {
        int dn = d + 8; if (dn >= D_EMB) dn = 0;
        const float* wn = Wp + (size_t)dn * DK + j;
        float n0 = wn[0], n1 = wn[DK], n2 = wn[2*DK], n3 = wn[3*DK];

        float4 e0 = *reinterpret_cast<const float4*>(&se[0][d]);
        float4 e1 = *reinterpret_cast<const float4*>(&se[1][d]);
        float4 e2 = *reinterpret_cast<const float4*>(&se[2][d]);
        float4 e3 = *reinterpret_cast<const float4*>(&se[3][d]);

        a0 = fmaf(e0.x, c0, a0); a0 = fmaf(e0.y, c1, a0);
        a0 = fmaf(e0.z, c2, a0); a0 = fmaf(e0.w, c3, a0);
        a1 = fmaf(e1.x, c0, a1); a1 = fmaf(e1.y, c1, a1);
        a1 = fmaf(e1.z, c2, a1); a1 = fmaf(e1.w, c3, a1);
        a2 = fmaf(e2.x, c0, a2); a2 = fmaf(e2.y, c1, a2);
        a2 = fmaf(e2.z, c2, a2); a2 = fmaf(e2.w, c3, a2);
        a3 = fmaf(e3.x, c0, a3); a3 = fmaf(e3.y, c1, a3);
        a3 = fmaf(e3.z, c2, a3); a3 = fmaf(e3.w, c3, a3);

        c0 = p0; c1 = p1; c2 = p2; c3 = p3;
        p0 = n0; p1 = n1; p2 = n2; p3 = n3;
    }

    float bj = bp[j];
    float o0 = a0 + bj, o1 = a1 + bj, o2 = a2 + bj, o3 = a3 + bj;
    float* dst = mat ? V : K;
    dst[(size_t)(r0 + 0) * DK + j] = o0;
    dst[(size_t)(r0 + 1) * DK + j] = o1;
    dst[(size_t)(r0 + 2) * DK + j] = o2;
    dst[(size_t)(r0 + 3) * DK + j] = o3;

    if (mat == 0) {
        const int wave = tid >> 6, l = tid & 63;
        float red[4] = { o0*o0, o1*o1, o2*o2, o3*o3 };
        wave_allred_arr(red);
        if (l == 0) {
            s_red[wave][0] = red[0]; s_red[wave][1] = red[1];
            s_red[wave][2] = red[2]; s_red[wave][3] = red[3];
        }
        __syncthreads();
        float t0 = s_red[0][0] + s_red[1][0] + s_red[2][0] + s_red[3][0];
        float t1 = s_red[0][1] + s_red[1][1] + s_red[2][1] + s_red[3][1];
        float t2 = s_red[0][2] + s_red[1][2] + s_red[2][2] + s_red[3][2];
        float t3 = s_red[0][3] + s_red[1][3] + s_red[2][3] + s_red[3][3];
        USrev[(size_t)(T - 1 - (r0 + 0)) * DK + j] = o0 * (1.0f / fmaxf(sqrtf(t0), 1e-12f));
        USrev[(size_t)(T - 1 - (r0 + 1)) * DK + j] = o1 * (1.0f / fmaxf(sqrtf(t1), 1e-12f));
        USrev[(size_t)(T - 1 - (r0 + 2)) * DK + j] = o2 * (1.0f / fmaxf(sqrtf(t2), 1e-12f));
        USrev[(size_t)(T - 1 - (r0 + 3)) * DK + j] = o3 * (1.0f / fmaxf(sqrtf(t3), 1e-12f));
    }
}

// ------------- Kernel 2: fused ufill + gram + bias + inversion (R5/R7 verbatim, validated) -------------
#define SU_STRIDE 260
__global__ __launch_bounds__(512) void mid_kernel(
    const float* __restrict__ K, const float* __restrict__ V,
    const float* __restrict__ USrev,
    float* __restrict__ UPrev, float* __restrict__ UPfwd,
    float* __restrict__ PV, float* __restrict__ SVv,
    float* __restrict__ AinvT, float* __restrict__ F1, float* __restrict__ biasF,
    int P, int NCS, int NCP)
{
    __shared__ __align__(16) float sU[64 * SU_STRIDE];
    __shared__ __align__(16) float sA[64 * 65];
    __shared__ float s_pd[64];
    __shared__ float s_sv[64];
    __shared__ float4 s_f1w[4][64];
    float* sX = sU;

    const int tid = threadIdx.x, wv = tid >> 6, l = tid & 63;
    const int bid = blockIdx.x;
    int type, m;
    if (bid < NCS)            { type = 0; m = bid; }
    else if (bid < NCS + NCP) { type = 1; m = bid - NCS; }
    else                      { type = 2; m = bid - NCS - NCP; }

    if (type == 2) {
        if (tid < 64) s_pd[tid] = powf(P_DECAY, (float)tid);
        __syncthreads();
    }

    // --- phase A ---
    if (type == 0) {
        const float4* U4 = reinterpret_cast<const float4*>(USrev) + (size_t)m * 4096;
        for (int idx = tid; idx < 4096; idx += 512) {
            float4 t = U4[idx];
            int row = idx >> 6, c4 = (idx & 63) << 2;
            *reinterpret_cast<float4*>(&sU[row * SU_STRIDE + c4]) = t;
        }
    } else if (type == 1) {
        if (tid < 256) {
            const float4* K4 = reinterpret_cast<const float4*>(K);
            for (int ii = 0; ii < 16; ii += 2) {
                const int iA = wv * 16 + ii, iB = iA + 1;
                const int pA = P - 1 - (64 * m + iA);
                const int pB = P - 1 - (64 * m + iB);
                float4 ka[5], kb[5];
                if (pA >= 0) {
#pragma unroll
                    for (int s = 0; s < 5; ++s) ka[s] = K4[(size_t)(5 * pA + s) * 64 + l];
                }
                if (pB >= 0) {
#pragma unroll
                    for (int s = 0; s < 5; ++s) kb[s] = K4[(size_t)(5 * pB + s) * 64 + l];
                }
                {
                    float4 u = make_float4(0.f, 0.f, 0.f, 0.f);
                    if (pA >= 0) {
                        float4 pk = make_float4(0.f, 0.f, 0.f, 0.f);
#pragma unroll
                        for (int s = 0; s < 5; ++s) {
                            pk.x += ka[s].x; pk.y += ka[s].y; pk.z += ka[s].z; pk.w += ka[s].w;
                        }
                        pk.x *= 0.2f; pk.y *= 0.2f; pk.z *= 0.2f; pk.w *= 0.2f;
                        float red[1] = { dot4v(pk, pk) };
                        wave_allred_arr(red);
                        float inv = 1.0f / fmaxf(sqrtf(red[0]), 1e-12f);
                        u = make_float4(pk.x * inv, pk.y * inv, pk.z * inv, pk.w * inv);
                    }
                    *reinterpret_cast<float4*>(&sU[iA * SU_STRIDE + 4 * l]) = u;
                    reinterpret_cast<float4*>(UPrev)[(size_t)(64 * m + iA) * 64 + l] = u;
                }
                {
                    float4 u = make_float4(0.f, 0.f, 0.f, 0.f);
                    if (pB >= 0) {
                        float4 pk = make_float4(0.f, 0.f, 0.f, 0.f);
#pragma unroll
                        for (int s = 0; s < 5; ++s) {
                            pk.x += kb[s].x; pk.y += kb[s].y; pk.z += kb[s].z; pk.w += kb[s].w;
                        }
                        pk.x *= 0.2f; pk.y *= 0.2f; pk.z *= 0.2f; pk.w *= 0.2f;
                        float red[1] = { dot4v(pk, pk) };
                        wave_allred_arr(red);
                        float inv = 1.0f / fmaxf(sqrtf(red[0]), 1e-12f);
                        u = make_float4(pk.x * inv, pk.y * inv, pk.z * inv, pk.w * inv);
                    }
                    *reinterpret_cast<float4*>(&sU[iB * SU_STRIDE + 4 * l]) = u;
                    reinterpret_cast<float4*>(UPrev)[(size_t)(64 * m + iB) * 64 + l] = u;
                }
            }
        }
    } else {
        if (tid < 256) {
            const float4* K4 = reinterpret_cast<const float4*>(K);
            const float4* V4 = reinterpret_cast<const float4*>(V);
            float4 f1p = make_float4(0.f, 0.f, 0.f, 0.f);
            for (int ii = 0; ii < 16; ii += 2) {
                const int iA = wv * 16 + ii, iB = iA + 1;
                const int pA = 64 * m + iA, pB = 64 * m + iB;
                float4 ka[5], va[5], kb[5], vb[5];
                if (pA < P) {
#pragma unroll
                    for (int s = 0; s < 5; ++s) {
                        ka[s] = K4[(size_t)(5 * pA + s) * 64 + l];
                        va[s] = V4[(size_t)(5 * pA + s) * 64 + l];
                    }
                }
                if (pB < P) {
#pragma unroll
                    for (int s = 0; s < 5; ++s) {
                        kb[s] = K4[(size_t)(5 * pB + s) * 64 + l];
                        vb[s] = V4[(size_t)(5 * pB + s) * 64 + l];
                    }
                }
                {
                    float4 u = make_float4(0.f, 0.f, 0.f, 0.f);
                    float sv = 0.f;
                    if (pA < P) {
                        float4 pk = make_float4(0.f, 0.f, 0.f, 0.f);
                        float4 pv = make_float4(0.f, 0.f, 0.f, 0.f);
#pragma unroll
                        for (int s = 0; s < 5; ++s) {
                            pk.x += ka[s].x; pk.y += ka[s].y; pk.z += ka[s].z; pk.w += ka[s].w;
                            pv.x += va[s].x; pv.y += va[s].y; pv.z += va[s].z; pv.w += va[s].w;
                        }
                        pk.x *= 0.2f; pk.y *= 0.2f; pk.z *= 0.2f; pk.w *= 0.2f;
                        pv.x *= 0.2f; pv.y *= 0.2f; pv.z *= 0.2f; pv.w *= 0.2f;
                        reinterpret_cast<float4*>(PV)[(size_t)pA * 64 + l] = pv;
                        float red[2] = { dot4v(pk, pk), pv.x + pv.y + pv.z + pv.w };
                        wave_allred_arr(red);
                        float inv = 1.0f / fmaxf(sqrtf(red[0]), 1e-12f);
                        u = make_float4(pk.x * inv, pk.y * inv, pk.z * inv, pk.w * inv);
                        sv = red[1];
                    }
                    *reinterpret_cast<float4*>(&sU[iA * SU_STRIDE + 4 * l]) = u;
                    reinterpret_cast<float4*>(UPfwd)[(size_t)(64 * m + iA) * 64 + l] = u;
                    if (l == 0) { s_sv[iA] = sv; SVv[64 * m + iA] = sv; }
                    float f = s_pd[63 - iA] * sv;
                    f1p.x = fmaf(f, u.x, f1p.x); f1p.y = fmaf(f, u.y, f1p.y);
                    f1p.z = fmaf(f, u.z, f1p.z); f1p.w = fmaf(f, u.w, f1p.w);
                }
                {
                    float4 u = make_float4(0.f, 0.f, 0.f, 0.f);
                    float sv = 0.f;
                    if (pB < P) {
                        float4 pk = make_float4(0.f, 0.f, 0.f, 0.f);
                        float4 pv = make_float4(0.f, 0.f, 0.f, 0.f);
#pragma unroll
                        for (int s = 0; s < 5; ++s) {
                            pk.x += kb[s].x; pk.y += kb[s].y; pk.z += kb[s].z; pk.w += kb[s].w;
                            pv.x += vb[s].x; pv.y += vb[s].y; pv.z += vb[s].z; pv.w += vb[s].w;
                        }
                        pk.x *= 0.2f; pk.y *= 0.2f; pk.z *= 0.2f; pk.w *= 0.2f;
                        pv.x *= 0.2f; pv.y *= 0.2f; pv.z *= 0.2f; pv.w *= 0.2f;
                        reinterpret_cast<float4*>(PV)[(size_t)pB * 64 + l] = pv;
                        float red[2] = { dot4v(pk, pk), pv.x + pv.y + pv.z + pv.w };
                        wave_allred_arr(red);
                        float inv = 1.0f / fmaxf(sqrtf(red[0]), 1e-12f);
                        u = make_float4(pk.x * inv, pk.y * inv, pk.z * inv, pk.w * inv);
                        sv = red[1];
                    }
                    *reinterpret_cast<float4*>(&sU[iB * SU_STRIDE + 4 * l]) = u;
                    reinterpret_cast<float4*>(UPfwd)[(size_t)(64 * m + iB) * 64 + l] = u;
                    if (l == 0) { s_sv[iB] = sv; SVv[64 * m + iB] = sv; }
                    float f = s_pd[63 - iB] * sv;
                    f1p.x = fmaf(f, u.x, f1p.x); f1p.y = fmaf(f, u.y, f1p.y);
                    f1p.z = fmaf(f, u.z, f1p.z); f1p.w = fmaf(f, u.w, f1p.w);
                }
            }
            s_f1w[wv][l] = f1p;
        }
    }
    __syncthreads();

    if (type == 2 && wv == 0) {
        float4 a = s_f1w[0][l], b = s_f1w[1][l], c = s_f1w[2][l], d = s_f1w[3][l];
        float4 tot = make_float4(a.x+b.x+c.x+d.x, a.y+b.y+c.y+d.y,
                                 a.z+b.z+c.z+d.z, a.w+b.w+c.w+d.w);
        reinterpret_cast<float4*>(F1)[(size_t)m * 64 + l] = tot;
    }

    // --- phase B: gram ---
    {
        const int i0 = (tid & 31) * 2;
        const int j0 = (tid >> 5) * 4;
        float g[2][4];
#pragma unroll
        for (int r = 0; r < 2; ++r)
#pragma unroll
            for (int c = 0; c < 4; ++c) g[r][c] = 0.f;
#pragma unroll 4
        for (int k4 = 0; k4 < 64; ++k4) {
            float4 A0 = *reinterpret_cast<const float4*>(&sU[(i0    ) * SU_STRIDE + 4*k4]);
            float4 A1 = *reinterpret_cast<const float4*>(&sU[(i0 + 1) * SU_STRIDE + 4*k4]);
            float4 B0 = *reinterpret_cast<const float4*>(&sU[(j0    ) * SU_STRIDE + 4*k4]);
            float4 B1 = *reinterpret_cast<const float4*>(&sU[(j0 + 1) * SU_STRIDE + 4*k4]);
            float4 B2 = *reinterpret_cast<const float4*>(&sU[(j0 + 2) * SU_STRIDE + 4*k4]);
            float4 B3 = *reinterpret_cast<const float4*>(&sU[(j0 + 3) * SU_STRIDE + 4*k4]);
            g[0][0] += dot4v(A0, B0); g[0][1] += dot4v(A0, B1);
            g[0][2] += dot4v(A0, B2); g[0][3] += dot4v(A0, B3);
            g[1][0] += dot4v(A1, B0); g[1][1] += dot4v(A1, B1);
            g[1][2] += dot4v(A1, B2); g[1][3] += dot4v(A1, B3);
        }
#pragma unroll
        for (int r = 0; r < 2; ++r)
#pragma unroll
            for (int c = 0; c < 4; ++c) {
                int gi = i0 + r, gj = j0 + c;
                float val = 0.f;
                if (gj < gi) {
                    val = ALPHA * g[r][c];
                    if (type == 2) val *= s_pd[gi - gj];
                }
                sA[gi * 65 + gj] = val;
            }
    }
    __syncthreads();

    if (type == 2 && wv == 0) {
        float dotb = 0.f;
#pragma unroll
        for (int jj = 0; jj < 64; ++jj)
            dotb = fmaf(sA[l * 65 + jj], s_sv[jj], dotb);
        biasF[m * 64 + l] = dotb * (1.0f / ALPHA);
    }

    // --- phase C: inversion ---
    {
        const int base = (wv & 3) * 16;
        float x[16];
#pragma unroll
        for (int r = 0; r < 16; ++r) x[r] = (base + r == l && wv < 4) ? 1.f : 0.f;
        for (int s = 0; s < 4; ++s) {
            if (wv == s) {
#pragma unroll
                for (int i = 1; i < 16; ++i)
#pragma unroll
                    for (int jj = 0; jj < 16; ++jj)
                        if (jj < i)
                            x[i] = fmaf(-sA[(base + i) * 65 + (base + jj)], x[jj], x[i]);
#pragma unroll
                for (int r = 0; r < 16; ++r) sX[(base + r) * 65 + l] = x[r];
            }
            __syncthreads();
            if (wv > s && wv < 4) {
#pragma unroll
                for (int i = 0; i < 16; ++i) {
                    float xi = sX[(s * 16 + i) * 65 + l];
#pragma unroll
                    for (int r = 0; r < 16; ++r)
                        x[r] = fmaf(-sA[(base + r) * 65 + (s * 16 + i)], xi, x[r]);
                }
            }
        }
    }
    __syncthreads();

    float* dstA = AinvT + (size_t)bid * 4096;
    for (int idx = tid; idx < 4096; idx += 512) {
        int jcol = idx >> 6, irow = idx & 63;
        dstA[idx] = sX[irow * 65 + jcol];
    }
}

// ------------- Kernel 3: accum2, ONE barrier per chain step (d-sharing) + accum -------------
// Per step: owning wave computes its 8 d-values (DPP, as R7) and shares them via s_d (double-
// buffered) -> ONE __syncthreads -> EVERY wave redundantly computes the full cl and s using the
// R10-validated grouped-sum order (bit-exact vs R7's cross-wave sums). X rows are preloaded one
// step ahead into 64 statically-indexed registers. 8 waves keep loads parallel (R10 lesson).
// Pure HIP, standard barriers only (R4/R9 lessons).
__global__ __launch_bounds__(512) void accum2_kernel(
    const float* __restrict__ V, const float* __restrict__ PV,
    const float* __restrict__ USrev, const float* __restrict__ UPrev,
    const float* __restrict__ UPfwd, const float* __restrict__ AinvT,
    const float* __restrict__ F1, const float* __restrict__ biasF,
    const float* __restrict__ q,
    float* __restrict__ out, int T, int P, int NCS, int NCP)
{
    __shared__ float s_d[2][64];
    __shared__ float s_powd[65];
    __shared__ float s_b[64];
    __shared__ float s_cpa[4][64];
    __shared__ float wc[64];
    __shared__ float s_gs[1];

    const int b = blockIdx.x, tid = threadIdx.x;
    const int wave = tid >> 6, l = tid & 63, wb = wave * 8;

    if (tid <= 64) s_powd[tid] = powf(P_DECAY, (float)tid);

    float4 q4 = reinterpret_cast<const float4*>(q)[l];
    float qs[1] = { dot4v(q4, q4) };
    wave_allred_arr(qs);
    float qinv = 1.0f / fmaxf(sqrtf(qs[0]), 1e-12f);
    float4 qn = make_float4(q4.x * qinv, q4.y * qinv, q4.z * qinv, q4.w * qinv);
    __syncthreads();

    int ci, chunk, realN; const float* src; float decay;
    if (b < NCS)              { ci = b;             chunk = b;        src = V;  decay = S_DECAY; realN = T; }
    else if (b < NCS + NCP)   { ci = b - NCS;       chunk = NCS + ci; src = PV; decay = P_DECAY; realN = P; }
    else                      { ci = b - NCS - NCP; chunk = NCS + ci; src = PV; decay = P_DECAY; realN = P; }

    // ---- preload accum-phase X rows (independent of chain) ----
    float xr[16];
    if (tid < 256) {
        const int part = tid >> 6, k = tid & 63;
        const float* Xc = AinvT + (size_t)chunk * 4096;
#pragma unroll
        for (int jj = 0; jj < 16; ++jj)
            xr[jj] = Xc[(part * 16 + jj) * 64 + k];
    }

    // ---- backward chain prefix: d shared via LDS, cl/s recomputed per wave (grouped, bit-exact) ----
    {
        const float4* U4; const float* Xb; float4 w1;
        if (b < NCS) {
            U4 = reinterpret_cast<const float4*>(USrev); Xb = AinvT; w1 = qn;
        } else if (b < NCS + NCP) {
            U4 = reinterpret_cast<const float4*>(UPrev); Xb = AinvT + (size_t)NCS * 4096; w1 = qn;
        } else {
            U4 = reinterpret_cast<const float4*>(UPrev); Xb = AinvT + (size_t)NCS * 4096;
            w1 = make_float4(1.f, 1.f, 1.f, 1.f);
        }
        float4 curU[8];
#pragma unroll
        for (int r = 0; r < 8; ++r)
            curU[r] = U4[(size_t)(wb + r) * 64 + l];
        float xall[64];
        if (ci > 0) {
#pragma unroll
            for (int j = 0; j < 64; ++j) xall[j] = Xb[(size_t)j * 64 + l];
        }
        for (int m = 0; m <= ci; ++m) {
            const size_t base = (size_t)m * 4096;
            float d[8];
#pragma unroll
            for (int r = 0; r < 8; ++r) d[r] = dot4v(curU[r], w1);
            wave_allred_arr(d);
            if (m == ci) {
                if (l == 0) {
#pragma unroll
                    for (int r = 0; r < 8; ++r) s_b[wb + r] = d[r];
                }
                break;
            }
            if (l == 0) {
#pragma unroll
                for (int r = 0; r < 8; ++r) s_d[m & 1][wb + r] = d[r];
            }
            // prefetch next step's own U rows (static addresses; drained at the barrier)
            float4 nxtU[8];
#pragma unroll
            for (int r = 0; r < 8; ++r)
                nxtU[r] = U4[(size_t)(m + 1) * 4096 + (size_t)(wb + r) * 64 + l];
            __syncthreads();   // ONE barrier per step
            // cl = sum over 8-row groups (same grouping/order as R7's cross-wave s_cp sum)
            float cl = 0.f;
#pragma unroll
            for (int g = 0; g < 8; ++g) {
                float cp = 0.f;
#pragma unroll
                for (int r = 0; r < 8; ++r)
                    cp = fmaf(xall[g * 8 + r], s_d[m & 1][g * 8 + r], cp);
                cl += cp;
            }
            // s = sum over 8-row groups (same grouping/order as R7's cross-wave s_part sum)
            float4 s = make_float4(0.f, 0.f, 0.f, 0.f);
#pragma unroll
            for (int g = 0; g < 8; ++g) {
                float4 ug[8];
#pragma unroll
                for (int r = 0; r < 8; ++r)
                    ug[r] = U4[base + (size_t)(g * 8 + r) * 64 + l];
                float4 part = make_float4(0.f, 0.f, 0.f, 0.f);
#pragma unroll
                for (int r = 0; r < 8; ++r) {
                    float cw = rl(cl, g * 8 + r);
                    part.x = fmaf(cw, ug[r].x, part.x); part.y = fmaf(cw, ug[r].y, part.y);
                    part.z = fmaf(cw, ug[r].z, part.z); part.w = fmaf(cw, ug[r].w, part.w);
                }
                s.x += part.x; s.y += part.y; s.z += part.z; s.w += part.w;
            }
            w1.x = fmaf(-ALPHA, s.x, w1.x); w1.y = fmaf(-ALPHA, s.y, w1.y);
            w1.z = fmaf(-ALPHA, s.z, w1.z); w1.w = fmaf(-ALPHA, s.w, w1.w);
#pragma unroll
            for (int r = 0; r < 8; ++r) curU[r] = nxtU[r];
            // preload next step's X rows (only needed if next step isn't the final d-only step)
            if (m + 1 < ci) {
#pragma unroll
                for (int j = 0; j < 64; ++j)
                    xall[j] = Xb[(size_t)(m + 1) * 4096 + (size_t)j * 64 + l];
            }
        }
    }
    __syncthreads();

    // ---- forward-y chain -> gscal (only BPB2-type blocks), same one-barrier scheme ----
    if (b >= NCS + NCP) {
        float4 y = make_float4(0.f, 0.f, 0.f, 0.f);
        const float4* Uf4 = reinterpret_cast<const float4*>(UPfwd);
        float4 cU[8];
#pragma unroll
        for (int r = 0; r < 8; ++r)
            cU[r] = Uf4[(size_t)(wb + r) * 64 + l];
        float xall[64];
#pragma unroll
        for (int j = 0; j < 64; ++j)
            xall[j] = AinvT[(size_t)(NCS + NCP) * 4096 + (size_t)j * 64 + l];
        for (int mm = 0; mm < NCP; ++mm) {
            const size_t ubase = (size_t)mm * 4096;
            float biasr[8];
#pragma unroll
            for (int r = 0; r < 8; ++r) biasr[r] = biasF[mm * 64 + wb + r];
            float4 f1 = reinterpret_cast<const float4*>(F1)[(size_t)mm * 64 + l];
            float d[8];
#pragma unroll
            for (int r = 0; r < 8; ++r) d[r] = dot4v(cU[r], y);
            wave_allred_arr(d);
#pragma unroll
            for (int r = 0; r < 8; ++r)
                d[r] = fmaf(s_powd[wb + r + 1], d[r], biasr[r]);
            if (l == 0) {
#pragma unroll
                for (int r = 0; r < 8; ++r) s_d[mm & 1][wb + r] = d[r];
            }
            float4 nU[8];
            if (mm + 1 < NCP) {
#pragma unroll
                for (int r = 0; r < 8; ++r)
                    nU[r] = Uf4[(size_t)(mm + 1) * 4096 + (size_t)(wb + r) * 64 + l];
            }
            __syncthreads();
            float cl = 0.f;
#pragma unroll
            for (int g = 0; g < 8; ++g) {
                float cp = 0.f;
#pragma unroll
                for (int r = 0; r < 8; ++r)
                    cp = fmaf(xall[g * 8 + r], s_d[mm & 1][g * 8 + r], cp);
                cl += cp;
            }
            float4 s = make_float4(0.f, 0.f, 0.f, 0.f);
#pragma unroll
            for (int g = 0; g < 8; ++g) {
                float4 ug[8];
#pragma unroll
                for (int r = 0; r < 8; ++r)
                    ug[r] = Uf4[ubase + (size_t)(g * 8 + r) * 64 + l];
                float4 part = make_float4(0.f, 0.f, 0.f, 0.f);
#pragma unroll
                for (int r = 0; r < 8; ++r) {
                    const int j = g * 8 + r;
                    float cw = s_powd[63 - j] * rl(cl, j);
                    part.x = fmaf(cw, ug[r].x, part.x); part.y = fmaf(cw, ug[r].y, part.y);
                    part.z = fmaf(cw, ug[r].z, part.z); part.w = fmaf(cw, ug[r].w, part.w);
                }
                s.x += part.x; s.y += part.y; s.z += part.z; s.w += part.w;
            }
            float d64 = s_powd[64];
            y.x = fmaf(d64, y.x, fmaf(-ALPHA, s.x, f1.x));
            y.y = fmaf(d64, y.y, fmaf(-ALPHA, s.y, f1.y));
            y.z = fmaf(d64, y.z, fmaf(-ALPHA, s.z, f1.z));
            y.w = fmaf(d64, y.w, fmaf(-ALPHA, s.w, f1.w));
            if (mm + 1 < NCP) {
#pragma unroll
                for (int r = 0; r < 8; ++r) cU[r] = nU[r];
#pragma unroll
                for (int j = 0; j < 64; ++j)
                    xall[j] = AinvT[(size_t)(NCS + NCP + mm + 1) * 4096 + (size_t)j * 64 + l];
            }
        }
        float fin[2] = { dot4v(y, y), dot4v(qn, y) };
        wave_allred_arr(fin);
        if (tid == 0) s_gs[0] = fin[1] / fmaxf(sqrtf(fin[0]), 2.56e-10f);
        __syncthreads();
    }

    // ---- accum (R7 body; Xc from preloaded registers) ----
    if (tid < 256) {
        const int part = tid >> 6, k = tid & 63;
        float cp = 0.f;
#pragma unroll
        for (int jj = 0; jj < 16; ++jj) {
            int j = part * 16 + jj;
            cp = fmaf(xr[jj], s_b[j], cp);
        }
        s_cpa[part][k] = cp;
    }
    __syncthreads();
    if (tid < 64) {
        float c = s_cpa[0][tid] + s_cpa[1][tid] + s_cpa[2][tid] + s_cpa[3][tid];
        wc[tid] = powf(decay, (float)(ci * 64 + tid)) * c;
    }
    __syncthreads();
    if (tid < 256) {
        const int k = tid;
        float acc = 0.f;
        for (int ii = 0; ii < 64; ++ii) {
            int i = ci * 64 + ii;
            if (i < realN)
                acc = fmaf(wc[ii], src[(size_t)(realN - 1 - i) * DK + k], acc);
        }
        float wlev;
        if (b < NCS)            wlev = 0.2f;
        else if (b < NCS + NCP) wlev = 0.3f;
        else                    wlev = (0.5f / 256.0f) * s_gs[0];
        atomicAdd(&out[k], wlev * acc);
    }
}

extern "C" void kernel_launch(void* const* d_in, const int* in_sizes, int n_in,
                              void* d_out, int out_size, void* d_ws, size_t ws_size,
                              hipStream_t stream) {
    const float* emb = (const float*)d_in[0];
    const float* q   = (const float*)d_in[1];
    const float* Wk  = (const float*)d_in[2];
    const float* bk  = (const float*)d_in[3];
    const float* Wv  = (const float*)d_in[4];
    const float* bv  = (const float*)d_in[5];

    const int T = in_sizes[0] / D_EMB;        // 1000
    const int P = T / 5;                      // 200
    const int NCS  = (T + 63) / 64;           // 16
    const int NCP  = (P + 63) / 64;           // 4
    const int PADS = NCS * 64;                // 1024
    const int PADP = NCP * 64;                // 256
    const int NCH  = NCS + 2 * NCP;           // 24

    float* ws    = (float*)d_ws;
    float* K     = ws;                               // T*256
    float* V     = K     + (size_t)T * DK;           // T*256
    float* PV    = V     + (size_t)T * DK;           // PADP*256
    float* USrev = PV    + (size_t)PADP * DK;        // PADS*256
    float* UPrev = USrev + (size_t)PADS * DK;        // PADP*256
    float* UPfwd = UPrev + (size_t)PADP * DK;        // PADP*256
    float* SVv   = UPfwd + (size_t)PADP * DK;        // PADP
    float* AinvT = SVv   + PADP;                     // NCH*4096
    float* F1    = AinvT + (size_t)NCH * 4096;       // NCP*256
    float* biasF = F1    + (size_t)NCP * 256;        // PADP

    prep_kernel<<<(T / 4) * 2 + 1, 256, 0, stream>>>(emb, Wk, bk, Wv, bv,
                                                     K, V, USrev, (float*)d_out, T);
    mid_kernel<<<NCH, 512, 0, stream>>>(K, V, USrev, UPrev, UPfwd, PV, SVv,
                                        AinvT, F1, biasF, P, NCS, NCP);
    accum2_kernel<<<NCH, 512, 0, stream>>>(V, PV, USrev, UPrev, UPfwd, AinvT,
                                           F1, biasF, q, (float*)d_out, T, P, NCS, NCP);
}

// Round 12
// 173.183 us; speedup vs baseline: 3.6498x; 3.6498x over previous
//
#include <hip/hip_runtime.h>
#include <hip/hip_bf16.h>

#define ALPHA   0.1f
#define S_DECAY 0.95f
#define P_DECAY 0.99f
#define D_EMB   768
#define DK      256

// ---- DPP wave-64 reduction helpers (validated rounds 1-8) ----
template<int ctrl, int row_mask>
__device__ __forceinline__ float dpp_add(float x) {
    int y = __builtin_amdgcn_update_dpp(0, __float_as_int(x), ctrl, row_mask, 0xF, true);
    return x + __int_as_float(y);
}

template<int N>
__device__ __forceinline__ void wave_allred_arr(float (&x)[N]) {
#pragma unroll
    for (int n = 0; n < N; ++n) x[n] = dpp_add<0xB1,  0xF>(x[n]);
#pragma unroll
    for (int n = 0; n < N; ++n) x[n] = dpp_add<0x4E,  0xF>(x[n]);
#pragma unroll
    for (int n = 0; n < N; ++n) x[n] = dpp_add<0x141, 0xF>(x[n]);
#pragma unroll
    for (int n = 0; n < N; ++n) x[n] = dpp_add<0x140, 0xF>(x[n]);
#pragma unroll
    for (int n = 0; n < N; ++n) x[n] = dpp_add<0x142, 0xA>(x[n]);
#pragma unroll
    for (int n = 0; n < N; ++n) x[n] = dpp_add<0x143, 0xC>(x[n]);
#pragma unroll
    for (int n = 0; n < N; ++n)
        x[n] = __int_as_float(__builtin_amdgcn_readlane(__float_as_int(x[n]), 63));
}

__device__ __forceinline__ float dot4v(const float4& a, const float4& b) {
    float t0 = a.x * b.x; t0 = fmaf(a.y, b.y, t0);
    float t1 = a.z * b.z; t1 = fmaf(a.w, b.w, t1);
    return t0 + t1;
}

__device__ __forceinline__ float rl(float x, int lane) {
    return __int_as_float(__builtin_amdgcn_readlane(__float_as_int(x), lane));
}

// ---------------- Kernel 1: GEMM, 4 rows x ONE matrix per block (validated, UNCHANGED) ----------------
__global__ __launch_bounds__(256) void prep_kernel(
    const float* __restrict__ emb,
    const float* __restrict__ Wk, const float* __restrict__ bk,
    const float* __restrict__ Wv, const float* __restrict__ bv,
    float* __restrict__ K, float* __restrict__ V, float* __restrict__ USrev,
    float* __restrict__ out, int T)
{
    const int tid = threadIdx.x;
    const int bid = blockIdx.x;
    const int NBLK = (T / 4) * 2;
    if (bid >= NBLK) {
        const int PADS = ((T + 63) / 64) * 64;
        for (int i = tid; i < (PADS - T) * DK; i += 256) USrev[(size_t)T * DK + i] = 0.f;
        out[tid] = 0.f;
        return;
    }
    const int mat = bid & 1;
    const int r0  = (bid >> 1) * 4;

    __shared__ float se[4][D_EMB];
    __shared__ float s_red[4][4];

    const float4* emb4 = reinterpret_cast<const float4*>(emb);
#pragma unroll
    for (int r = 0; r < 4; ++r) {
        if (tid < D_EMB / 4)
            reinterpret_cast<float4*>(se[r])[tid] = emb4[(size_t)(r0 + r) * (D_EMB / 4) + tid];
    }
    __syncthreads();

    const float* Wp = mat ? Wv : Wk;
    const float* bp = mat ? bv : bk;
    const int j = tid;

    float a0 = 0.f, a1 = 0.f, a2 = 0.f, a3 = 0.f;
    float c0 = Wp[j],        c1 = Wp[j + DK],     c2 = Wp[j + 2*DK], c3 = Wp[j + 3*DK];
    float p0 = Wp[j + 4*DK], p1 = Wp[j + 5*DK],   p2 = Wp[j + 6*DK], p3 = Wp[j + 7*DK];

    for (int d = 0; d < D_EMB; d += 4) {
        int dn = d + 8; if (dn >= D_EMB) dn = 0;
        const float* wn = Wp + (size_t)dn * DK + j;
        float n0 = wn[0], n1 = wn[DK], n2 = wn[2*DK], n3 = wn[3*DK];

        float4 e0 = *reinterpret_cast<const float4*>(&se[0][d]);
        float4 e1 = *reinterpret_cast<const float4*>(&se[1][d]);
        float4 e2 = *reinterpret_cast<const float4*>(&se[2][d]);
        float4 e3 = *reinterpret_cast<const float4*>(&se[3][d]);

        a0 = fmaf(e0.x, c0, a0); a0 = fmaf(e0.y, c1, a0);
        a0 = fmaf(e0.z, c2, a0); a0 = fmaf(e0.w, c3, a0);
        a1 = fmaf(e1.x, c0, a1); a1 = fmaf(e1.y, c1, a1);
        a1 = fmaf(e1.z, c2, a1); a1 = fmaf(e1.w, c3, a1);
        a2 = fmaf(e2.x, c0, a2); a2 = fmaf(e2.y, c1, a2);
        a2 = fmaf(e2.z, c2, a2); a2 = fmaf(e2.w, c3, a2);
        a3 = fmaf(e3.x, c0, a3); a3 = fmaf(e3.y, c1, a3);
        a3 = fmaf(e3.z, c2, a3); a3 = fmaf(e3.w, c3, a3);

        c0 = p0; c1 = p1; c2 = p2; c3 = p3;
        p0 = n0; p1 = n1; p2 = n2; p3 = n3;
    }

    float bj = bp[j];
    float o0 = a0 + bj, o1 = a1 + bj, o2 = a2 + bj, o3 = a3 + bj;
    float* dst = mat ? V : K;
    dst[(size_t)(r0 + 0) * DK + j] = o0;
    dst[(size_t)(r0 + 1) * DK + j] = o1;
    dst[(size_t)(r0 + 2) * DK + j] = o2;
    dst[(size_t)(r0 + 3) * DK + j] = o3;

    if (mat == 0) {
        const int wave = tid >> 6, l = tid & 63;
        float red[4] = { o0*o0, o1*o1, o2*o2, o3*o3 };
        wave_allred_arr(red);
        if (l == 0) {
            s_red[wave][0] = red[0]; s_red[wave][1] = red[1];
            s_red[wave][2] = red[2]; s_red[wave][3] = red[3];
        }
        __syncthreads();
        float t0 = s_red[0][0] + s_red[1][0] + s_red[2][0] + s_red[3][0];
        float t1 = s_red[0][1] + s_red[1][1] + s_red[2][1] + s_red[3][1];
        float t2 = s_red[0][2] + s_red[1][2] + s_red[2][2] + s_red[3][2];
        float t3 = s_red[0][3] + s_red[1][3] + s_red[2][3] + s_red[3][3];
        USrev[(size_t)(T - 1 - (r0 + 0)) * DK + j] = o0 * (1.0f / fmaxf(sqrtf(t0), 1e-12f));
        USrev[(size_t)(T - 1 - (r0 + 1)) * DK + j] = o1 * (1.0f / fmaxf(sqrtf(t1), 1e-12f));
        USrev[(size_t)(T - 1 - (r0 + 2)) * DK + j] = o2 * (1.0f / fmaxf(sqrtf(t2), 1e-12f));
        USrev[(size_t)(T - 1 - (r0 + 3)) * DK + j] = o3 * (1.0f / fmaxf(sqrtf(t3), 1e-12f));
    }
}

// ------------- Kernel 2: fused ufill + gram + bias + inversion (R5/R7 verbatim, validated) -------------
#define SU_STRIDE 260
__global__ __launch_bounds__(512) void mid_kernel(
    const float* __restrict__ K, const float* __restrict__ V,
    const float* __restrict__ USrev,
    float* __restrict__ UPrev, float* __restrict__ UPfwd,
    float* __restrict__ PV, float* __restrict__ SVv,
    float* __restrict__ AinvT, float* __restrict__ F1, float* __restrict__ biasF,
    int P, int NCS, int NCP)
{
    __shared__ __align__(16) float sU[64 * SU_STRIDE];
    __shared__ __align__(16) float sA[64 * 65];
    __shared__ float s_pd[64];
    __shared__ float s_sv[64];
    __shared__ float4 s_f1w[4][64];
    float* sX = sU;

    const int tid = threadIdx.x, wv = tid >> 6, l = tid & 63;
    const int bid = blockIdx.x;
    int type, m;
    if (bid < NCS)            { type = 0; m = bid; }
    else if (bid < NCS + NCP) { type = 1; m = bid - NCS; }
    else                      { type = 2; m = bid - NCS - NCP; }

    if (type == 2) {
        if (tid < 64) s_pd[tid] = powf(P_DECAY, (float)tid);
        __syncthreads();
    }

    // --- phase A ---
    if (type == 0) {
        const float4* U4 = reinterpret_cast<const float4*>(USrev) + (size_t)m * 4096;
        for (int idx = tid; idx < 4096; idx += 512) {
            float4 t = U4[idx];
            int row = idx >> 6, c4 = (idx & 63) << 2;
            *reinterpret_cast<float4*>(&sU[row * SU_STRIDE + c4]) = t;
        }
    } else if (type == 1) {
        if (tid < 256) {
            const float4* K4 = reinterpret_cast<const float4*>(K);
            for (int ii = 0; ii < 16; ii += 2) {
                const int iA = wv * 16 + ii, iB = iA + 1;
                const int pA = P - 1 - (64 * m + iA);
                const int pB = P - 1 - (64 * m + iB);
                float4 ka[5], kb[5];
                if (pA >= 0) {
#pragma unroll
                    for (int s = 0; s < 5; ++s) ka[s] = K4[(size_t)(5 * pA + s) * 64 + l];
                }
                if (pB >= 0) {
#pragma unroll
                    for (int s = 0; s < 5; ++s) kb[s] = K4[(size_t)(5 * pB + s) * 64 + l];
                }
                {
                    float4 u = make_float4(0.f, 0.f, 0.f, 0.f);
                    if (pA >= 0) {
                        float4 pk = make_float4(0.f, 0.f, 0.f, 0.f);
#pragma unroll
                        for (int s = 0; s < 5; ++s) {
                            pk.x += ka[s].x; pk.y += ka[s].y; pk.z += ka[s].z; pk.w += ka[s].w;
                        }
                        pk.x *= 0.2f; pk.y *= 0.2f; pk.z *= 0.2f; pk.w *= 0.2f;
                        float red[1] = { dot4v(pk, pk) };
                        wave_allred_arr(red);
                        float inv = 1.0f / fmaxf(sqrtf(red[0]), 1e-12f);
                        u = make_float4(pk.x * inv, pk.y * inv, pk.z * inv, pk.w * inv);
                    }
                    *reinterpret_cast<float4*>(&sU[iA * SU_STRIDE + 4 * l]) = u;
                    reinterpret_cast<float4*>(UPrev)[(size_t)(64 * m + iA) * 64 + l] = u;
                }
                {
                    float4 u = make_float4(0.f, 0.f, 0.f, 0.f);
                    if (pB >= 0) {
                        float4 pk = make_float4(0.f, 0.f, 0.f, 0.f);
#pragma unroll
                        for (int s = 0; s < 5; ++s) {
                            pk.x += kb[s].x; pk.y += kb[s].y; pk.z += kb[s].z; pk.w += kb[s].w;
                        }
                        pk.x *= 0.2f; pk.y *= 0.2f; pk.z *= 0.2f; pk.w *= 0.2f;
                        float red[1] = { dot4v(pk, pk) };
                        wave_allred_arr(red);
                        float inv = 1.0f / fmaxf(sqrtf(red[0]), 1e-12f);
                        u = make_float4(pk.x * inv, pk.y * inv, pk.z * inv, pk.w * inv);
                    }
                    *reinterpret_cast<float4*>(&sU[iB * SU_STRIDE + 4 * l]) = u;
                    reinterpret_cast<float4*>(UPrev)[(size_t)(64 * m + iB) * 64 + l] = u;
                }
            }
        }
    } else {
        if (tid < 256) {
            const float4* K4 = reinterpret_cast<const float4*>(K);
            const float4* V4 = reinterpret_cast<const float4*>(V);
            float4 f1p = make_float4(0.f, 0.f, 0.f, 0.f);
            for (int ii = 0; ii < 16; ii += 2) {
                const int iA = wv * 16 + ii, iB = iA + 1;
                const int pA = 64 * m + iA, pB = 64 * m + iB;
                float4 ka[5], va[5], kb[5], vb[5];
                if (pA < P) {
#pragma unroll
                    for (int s = 0; s < 5; ++s) {
                        ka[s] = K4[(size_t)(5 * pA + s) * 64 + l];
                        va[s] = V4[(size_t)(5 * pA + s) * 64 + l];
                    }
                }
                if (pB < P) {
#pragma unroll
                    for (int s = 0; s < 5; ++s) {
                        kb[s] = K4[(size_t)(5 * pB + s) * 64 + l];
                        vb[s] = V4[(size_t)(5 * pB + s) * 64 + l];
                    }
                }
                {
                    float4 u = make_float4(0.f, 0.f, 0.f, 0.f);
                    float sv = 0.f;
                    if (pA < P) {
                        float4 pk = make_float4(0.f, 0.f, 0.f, 0.f);
                        float4 pv = make_float4(0.f, 0.f, 0.f, 0.f);
#pragma unroll
                        for (int s = 0; s < 5; ++s) {
                            pk.x += ka[s].x; pk.y += ka[s].y; pk.z += ka[s].z; pk.w += ka[s].w;
                            pv.x += va[s].x; pv.y += va[s].y; pv.z += va[s].z; pv.w += va[s].w;
                        }
                        pk.x *= 0.2f; pk.y *= 0.2f; pk.z *= 0.2f; pk.w *= 0.2f;
                        pv.x *= 0.2f; pv.y *= 0.2f; pv.z *= 0.2f; pv.w *= 0.2f;
                        reinterpret_cast<float4*>(PV)[(size_t)pA * 64 + l] = pv;
                        float red[2] = { dot4v(pk, pk), pv.x + pv.y + pv.z + pv.w };
                        wave_allred_arr(red);
                        float inv = 1.0f / fmaxf(sqrtf(red[0]), 1e-12f);
                        u = make_float4(pk.x * inv, pk.y * inv, pk.z * inv, pk.w * inv);
                        sv = red[1];
                    }
                    *reinterpret_cast<float4*>(&sU[iA * SU_STRIDE + 4 * l]) = u;
                    reinterpret_cast<float4*>(UPfwd)[(size_t)(64 * m + iA) * 64 + l] = u;
                    if (l == 0) { s_sv[iA] = sv; SVv[64 * m + iA] = sv; }
                    float f = s_pd[63 - iA] * sv;
                    f1p.x = fmaf(f, u.x, f1p.x); f1p.y = fmaf(f, u.y, f1p.y);
                    f1p.z = fmaf(f, u.z, f1p.z); f1p.w = fmaf(f, u.w, f1p.w);
                }
                {
                    float4 u = make_float4(0.f, 0.f, 0.f, 0.f);
                    float sv = 0.f;
                    if (pB < P) {
                        float4 pk = make_float4(0.f, 0.f, 0.f, 0.f);
                        float4 pv = make_float4(0.f, 0.f, 0.f, 0.f);
#pragma unroll
                        for (int s = 0; s < 5; ++s) {
                            pk.x += kb[s].x; pk.y += kb[s].y; pk.z += kb[s].z; pk.w += kb[s].w;
                            pv.x += vb[s].x; pv.y += vb[s].y; pv.z += vb[s].z; pv.w += vb[s].w;
                        }
                        pk.x *= 0.2f; pk.y *= 0.2f; pk.z *= 0.2f; pk.w *= 0.2f;
                        pv.x *= 0.2f; pv.y *= 0.2f; pv.z *= 0.2f; pv.w *= 0.2f;
                        reinterpret_cast<float4*>(PV)[(size_t)pB * 64 + l] = pv;
                        float red[2] = { dot4v(pk, pk), pv.x + pv.y + pv.z + pv.w };
                        wave_allred_arr(red);
                        float inv = 1.0f / fmaxf(sqrtf(red[0]), 1e-12f);
                        u = make_float4(pk.x * inv, pk.y * inv, pk.z * inv, pk.w * inv);
                        sv = red[1];
                    }
                    *reinterpret_cast<float4*>(&sU[iB * SU_STRIDE + 4 * l]) = u;
                    reinterpret_cast<float4*>(UPfwd)[(size_t)(64 * m + iB) * 64 + l] = u;
                    if (l == 0) { s_sv[iB] = sv; SVv[64 * m + iB] = sv; }
                    float f = s_pd[63 - iB] * sv;
                    f1p.x = fmaf(f, u.x, f1p.x); f1p.y = fmaf(f, u.y, f1p.y);
                    f1p.z = fmaf(f, u.z, f1p.z); f1p.w = fmaf(f, u.w, f1p.w);
                }
            }
            s_f1w[wv][l] = f1p;
        }
    }
    __syncthreads();

    if (type == 2 && wv == 0) {
        float4 a = s_f1w[0][l], b = s_f1w[1][l], c = s_f1w[2][l], d = s_f1w[3][l];
        float4 tot = make_float4(a.x+b.x+c.x+d.x, a.y+b.y+c.y+d.y,
                                 a.z+b.z+c.z+d.z, a.w+b.w+c.w+d.w);
        reinterpret_cast<float4*>(F1)[(size_t)m * 64 + l] = tot;
    }

    // --- phase B: gram ---
    {
        const int i0 = (tid & 31) * 2;
        const int j0 = (tid >> 5) * 4;
        float g[2][4];
#pragma unroll
        for (int r = 0; r < 2; ++r)
#pragma unroll
            for (int c = 0; c < 4; ++c) g[r][c] = 0.f;
#pragma unroll 4
        for (int k4 = 0; k4 < 64; ++k4) {
            float4 A0 = *reinterpret_cast<const float4*>(&sU[(i0    ) * SU_STRIDE + 4*k4]);
            float4 A1 = *reinterpret_cast<const float4*>(&sU[(i0 + 1) * SU_STRIDE + 4*k4]);
            float4 B0 = *reinterpret_cast<const float4*>(&sU[(j0    ) * SU_STRIDE + 4*k4]);
            float4 B1 = *reinterpret_cast<const float4*>(&sU[(j0 + 1) * SU_STRIDE + 4*k4]);
            float4 B2 = *reinterpret_cast<const float4*>(&sU[(j0 + 2) * SU_STRIDE + 4*k4]);
            float4 B3 = *reinterpret_cast<const float4*>(&sU[(j0 + 3) * SU_STRIDE + 4*k4]);
            g[0][0] += dot4v(A0, B0); g[0][1] += dot4v(A0, B1);
            g[0][2] += dot4v(A0, B2); g[0][3] += dot4v(A0, B3);
            g[1][0] += dot4v(A1, B0); g[1][1] += dot4v(A1, B1);
            g[1][2] += dot4v(A1, B2); g[1][3] += dot4v(A1, B3);
        }
#pragma unroll
        for (int r = 0; r < 2; ++r)
#pragma unroll
            for (int c = 0; c < 4; ++c) {
                int gi = i0 + r, gj = j0 + c;
                float val = 0.f;
                if (gj < gi) {
                    val = ALPHA * g[r][c];
                    if (type == 2) val *= s_pd[gi - gj];
                }
                sA[gi * 65 + gj] = val;
            }
    }
    __syncthreads();

    if (type == 2 && wv == 0) {
        float dotb = 0.f;
#pragma unroll
        for (int jj = 0; jj < 64; ++jj)
            dotb = fmaf(sA[l * 65 + jj], s_sv[jj], dotb);
        biasF[m * 64 + l] = dotb * (1.0f / ALPHA);
    }

    // --- phase C: inversion ---
    {
        const int base = (wv & 3) * 16;
        float x[16];
#pragma unroll
        for (int r = 0; r < 16; ++r) x[r] = (base + r == l && wv < 4) ? 1.f : 0.f;
        for (int s = 0; s < 4; ++s) {
            if (wv == s) {
#pragma unroll
                for (int i = 1; i < 16; ++i)
#pragma unroll
                    for (int jj = 0; jj < 16; ++jj)
                        if (jj < i)
                            x[i] = fmaf(-sA[(base + i) * 65 + (base + jj)], x[jj], x[i]);
#pragma unroll
                for (int r = 0; r < 16; ++r) sX[(base + r) * 65 + l] = x[r];
            }
            __syncthreads();
            if (wv > s && wv < 4) {
#pragma unroll
                for (int i = 0; i < 16; ++i) {
                    float xi = sX[(s * 16 + i) * 65 + l];
#pragma unroll
                    for (int r = 0; r < 16; ++r)
                        x[r] = fmaf(-sA[(base + r) * 65 + (s * 16 + i)], xi, x[r]);
                }
            }
        }
    }
    __syncthreads();

    float* dstA = AinvT + (size_t)bid * 4096;
    for (int idx = tid; idx < 4096; idx += 512) {
        int jcol = idx >> 6, irow = idx & 63;
        dstA[idx] = sX[irow * 65 + jcol];
    }
}

// ------------- Kernel 3: accum2 = per-block redundant solve prefix + accum (R7 verbatim) -------------
__global__ __launch_bounds__(512) void accum2_kernel(
    const float* __restrict__ V, const float* __restrict__ PV,
    const float* __restrict__ USrev, const float* __restrict__ UPrev,
    const float* __restrict__ UPfwd, const float* __restrict__ AinvT,
    const float* __restrict__ F1, const float* __restrict__ biasF,
    const float* __restrict__ q,
    float* __restrict__ out, int T, int P, int NCS, int NCP)
{
    __shared__ float s_cp[8][64];
    __shared__ float4 s_part[8][64];
    __shared__ float s_powd[65];
    __shared__ float s_b[64];
    __shared__ float s_cpa[4][64];
    __shared__ float wc[64];
    __shared__ float s_gs[1];

    const int b = blockIdx.x, tid = threadIdx.x;
    const int wave = tid >> 6, l = tid & 63, wb = wave * 8;

    if (tid <= 64) s_powd[tid] = powf(P_DECAY, (float)tid);

    float4 q4 = reinterpret_cast<const float4*>(q)[l];
    float qs[1] = { dot4v(q4, q4) };
    wave_allred_arr(qs);
    float qinv = 1.0f / fmaxf(sqrtf(qs[0]), 1e-12f);
    float4 qn = make_float4(q4.x * qinv, q4.y * qinv, q4.z * qinv, q4.w * qinv);
    __syncthreads();

    int ci, chunk, realN; const float* src; float decay;
    if (b < NCS)              { ci = b;             chunk = b;        src = V;  decay = S_DECAY; realN = T; }
    else if (b < NCS + NCP)   { ci = b - NCS;       chunk = NCS + ci; src = PV; decay = P_DECAY; realN = P; }
    else                      { ci = b - NCS - NCP; chunk = NCS + ci; src = PV; decay = P_DECAY; realN = P; }

    // ---- backward chain prefix (single RHS; element-wise identical to solve's chains) ----
    {
        const float4* U4; const float* Xb; float4 w1;
        if (b < NCS) {
            U4 = reinterpret_cast<const float4*>(USrev); Xb = AinvT; w1 = qn;
        } else if (b < NCS + NCP) {
            U4 = reinterpret_cast<const float4*>(UPrev); Xb = AinvT + (size_t)NCS * 4096; w1 = qn;
        } else {
            U4 = reinterpret_cast<const float4*>(UPrev); Xb = AinvT + (size_t)NCS * 4096;
            w1 = make_float4(1.f, 1.f, 1.f, 1.f);
        }
        for (int m = 0; m <= ci; ++m) {
            float4 curU[8];
#pragma unroll
            for (int r = 0; r < 8; ++r)
                curU[r] = U4[(size_t)m * 4096 + (size_t)(wb + r) * 64 + l];
            float d[8];
#pragma unroll
            for (int r = 0; r < 8; ++r) d[r] = dot4v(curU[r], w1);
            wave_allred_arr(d);
            if (m == ci) {
                if (l == 0) {
#pragma unroll
                    for (int r = 0; r < 8; ++r) s_b[wb + r] = d[r];
                }
                break;
            }
            float curX[8];
#pragma unroll
            for (int r = 0; r < 8; ++r)
                curX[r] = Xb[(size_t)m * 4096 + (size_t)(wb + r) * 64 + l];
            float cp = 0.f;
#pragma unroll
            for (int r = 0; r < 8; ++r) cp = fmaf(curX[r], d[r], cp);
            s_cp[wave][l] = cp;
            __syncthreads();
            float cl = 0.f;
#pragma unroll
            for (int w = 0; w < 8; ++w) cl += s_cp[w][l];
            float4 part = make_float4(0.f, 0.f, 0.f, 0.f);
#pragma unroll
            for (int r = 0; r < 8; ++r) {
                float cw = rl(cl, wb + r);
                part.x = fmaf(cw, curU[r].x, part.x); part.y = fmaf(cw, curU[r].y, part.y);
                part.z = fmaf(cw, curU[r].z, part.z); part.w = fmaf(cw, curU[r].w, part.w);
            }
            s_part[wave][l] = part;
            __syncthreads();
            float4 s = make_float4(0.f, 0.f, 0.f, 0.f);
#pragma unroll
            for (int w = 0; w < 8; ++w) {
                float4 p = s_part[w][l];
                s.x += p.x; s.y += p.y; s.z += p.z; s.w += p.w;
            }
            w1.x = fmaf(-ALPHA, s.x, w1.x); w1.y = fmaf(-ALPHA, s.y, w1.y);
            w1.z = fmaf(-ALPHA, s.z, w1.z); w1.w = fmaf(-ALPHA, s.w, w1.w);
        }
    }
    __syncthreads();

    // ---- forward-y chain -> gscal (only the BPB2-type blocks; independent of backward) ----
    if (b >= NCS + NCP) {
        float4 y = make_float4(0.f, 0.f, 0.f, 0.f);
        const float4* Uf4 = reinterpret_cast<const float4*>(UPfwd);
        for (int mm = 0; mm < NCP; ++mm) {
            float4 cU[8]; float cX[8];
#pragma unroll
            for (int r = 0; r < 8; ++r) {
                cU[r] = Uf4[(size_t)mm * 4096 + (size_t)(wb + r) * 64 + l];
                cX[r] = AinvT[(size_t)(NCS + NCP + mm) * 4096 + (size_t)(wb + r) * 64 + l];
            }
            float biasr[8];
#pragma unroll
            for (int r = 0; r < 8; ++r) biasr[r] = biasF[mm * 64 + wb + r];
            float4 f1 = reinterpret_cast<const float4*>(F1)[(size_t)mm * 64 + l];
            float d[8];
#pragma unroll
            for (int r = 0; r < 8; ++r) d[r] = dot4v(cU[r], y);
            wave_allred_arr(d);
#pragma unroll
            for (int r = 0; r < 8; ++r)
                d[r] = fmaf(s_powd[wb + r + 1], d[r], biasr[r]);
            float cp = 0.f;
#pragma unroll
            for (int r = 0; r < 8; ++r) cp = fmaf(cX[r], d[r], cp);
            s_cp[wave][l] = cp;
            __syncthreads();
            float cl = 0.f;
#pragma unroll
            for (int w = 0; w < 8; ++w) cl += s_cp[w][l];
            float4 part = make_float4(0.f, 0.f, 0.f, 0.f);
#pragma unroll
            for (int r = 0; r < 8; ++r) {
                float cw = s_powd[63 - (wb + r)] * rl(cl, wb + r);
                part.x = fmaf(cw, cU[r].x, part.x); part.y = fmaf(cw, cU[r].y, part.y);
                part.z = fmaf(cw, cU[r].z, part.z); part.w = fmaf(cw, cU[r].w, part.w);
            }
            s_part[wave][l] = part;
            __syncthreads();
            float4 s = make_float4(0.f, 0.f, 0.f, 0.f);
#pragma unroll
            for (int w = 0; w < 8; ++w) {
                float4 p = s_part[w][l];
                s.x += p.x; s.y += p.y; s.z += p.z; s.w += p.w;
            }
            float d64 = s_powd[64];
            y.x = fmaf(d64, y.x, fmaf(-ALPHA, s.x, f1.x));
            y.y = fmaf(d64, y.y, fmaf(-ALPHA, s.y, f1.y));
            y.z = fmaf(d64, y.z, fmaf(-ALPHA, s.z, f1.z));
            y.w = fmaf(d64, y.w, fmaf(-ALPHA, s.w, f1.w));
        }
        float fin[2] = { dot4v(y, y), dot4v(qn, y) };
        wave_allred_arr(fin);
        if (tid == 0) s_gs[0] = fin[1] / fmaxf(sqrtf(fin[0]), 2.56e-10f);
        __syncthreads();
    }

    // ---- accum ----
    if (tid < 256) {
        const int part = tid >> 6, k = tid & 63;
        const float* Xc = AinvT + (size_t)chunk * 4096;
        float cp = 0.f;
#pragma unroll
        for (int jj = 0; jj < 16; ++jj) {
            int j = part * 16 + jj;
            cp = fmaf(Xc[j * 64 + k], s_b[j], cp);
        }
        s_cpa[part][k] = cp;
    }
    __syncthreads();
    if (tid < 64) {
        float c = s_cpa[0][tid] + s_cpa[1][tid] + s_cpa[2][tid] + s_cpa[3][tid];
        wc[tid] = powf(decay, (float)(ci * 64 + tid)) * c;
    }
    __syncthreads();
    if (tid < 256) {
        const int k = tid;
        float acc = 0.f;
        for (int ii = 0; ii < 64; ++ii) {
            int i = ci * 64 + ii;
            if (i < realN)
                acc = fmaf(wc[ii], src[(size_t)(realN - 1 - i) * DK + k], acc);
        }
        float wlev;
        if (b < NCS)            wlev = 0.2f;
        else if (b < NCS + NCP) wlev = 0.3f;
        else                    wlev = (0.5f / 256.0f) * s_gs[0];
        atomicAdd(&out[k], wlev * acc);
    }
}

extern "C" void kernel_launch(void* const* d_in, const int* in_sizes, int n_in,
                              void* d_out, int out_size, void* d_ws, size_t ws_size,
                              hipStream_t stream) {
    const float* emb = (const float*)d_in[0];
    const float* q   = (const float*)d_in[1];
    const float* Wk  = (const float*)d_in[2];
    const float* bk  = (const float*)d_in[3];
    const float* Wv  = (const float*)d_in[4];
    const float* bv  = (const float*)d_in[5];

    const int T = in_sizes[0] / D_EMB;        // 1000
    const int P = T / 5;                      // 200
    const int NCS  = (T + 63) / 64;           // 16
    const int NCP  = (P + 63) / 64;           // 4
    const int PADS = NCS * 64;                // 1024
    const int PADP = NCP * 64;                // 256
    const int NCH  = NCS + 2 * NCP;           // 24

    float* ws    = (float*)d_ws;
    float* K     = ws;                               // T*256
    float* V     = K     + (size_t)T * DK;           // T*256
    float* PV    = V     + (size_t)T * DK;           // PADP*256
    float* USrev = PV    + (size_t)PADP * DK;        // PADS*256
    float* UPrev = USrev + (size_t)PADS * DK;        // PADP*256
    float* UPfwd = UPrev + (size_t)PADP * DK;        // PADP*256
    float* SVv   = UPfwd + (size_t)PADP * DK;        // PADP
    float* AinvT = SVv   + PADP;                     // NCH*4096
    float* F1    = AinvT + (size_t)NCH * 4096;       // NCP*256
    float* biasF = F1    + (size_t)NCP * 256;        // PADP

    prep_kernel<<<(T / 4) * 2 + 1, 256, 0, stream>>>(emb, Wk, bk, Wv, bv,
                                                     K, V, USrev, (float*)d_out, T);
    mid_kernel<<<NCH, 512, 0, stream>>>(K, V, USrev, UPrev, UPfwd, PV, SVv,
                                        AinvT, F1, biasF, P, NCS, NCP);
    accum2_kernel<<<NCH, 512, 0, stream>>>(V, PV, USrev, UPrev, UPfwd, AinvT,
                                           F1, biasF, q, (float*)d_out, T, P, NCS, NCP);
}